// Round 1
// baseline (778.852 us; speedup 1.0000x reference)
//
#include <hip/hip_runtime.h>

// Problem constants: B=2, S=2048 -> T=4096 tokens; D=1024, H=4096, E=8, top-2.
#define T_TOK 4096
#define DIM   1024
#define HID   4096
#define NEXP  8

typedef unsigned short u16;
typedef __attribute__((ext_vector_type(8))) short short8;   // 8 bf16 (4 VGPRs) MFMA frag
typedef __attribute__((ext_vector_type(4))) float f32x4;
typedef __attribute__((ext_vector_type(4))) unsigned short u16x4;

typedef __attribute__((address_space(3))) unsigned int lds_uint;
typedef const __attribute__((address_space(1))) unsigned int gbl_uint;

__device__ __forceinline__ u16 f2bf(float f) {
    union { float f; unsigned int u; } v; v.f = f;
    unsigned int r = v.u + 0x7fffu + ((v.u >> 16) & 1u);   // RNE
    return (u16)(r >> 16);
}

// ---------------- transpose + cast fp32 [R][C] -> bf16 [C][R], per expert (blockIdx.z)
__global__ __launch_bounds__(256)
void transpose_cast(const float* __restrict__ in, u16* __restrict__ out, int R, int C) {
    __shared__ float tile[32][33];
    size_t mo = (size_t)blockIdx.z * R * C;
    const float* ip = in + mo;
    u16* op = out + mo;
    int c0 = blockIdx.x * 32, r0 = blockIdx.y * 32;
    int tx = threadIdx.x, ty = threadIdx.y;   // (32,8)
#pragma unroll
    for (int i = 0; i < 4; ++i)
        tile[ty + 8*i][tx] = ip[(size_t)(r0 + ty + 8*i) * C + c0 + tx];
    __syncthreads();
#pragma unroll
    for (int i = 0; i < 4; ++i)
        op[(size_t)(c0 + ty + 8*i) * R + r0 + tx] = f2bf(tile[tx][ty + 8*i]);
}

// ---------------- router: logits -> softmax -> top2 -> renormalized gates
__global__ __launch_bounds__(256)
void router_k(const float* __restrict__ x, const float* __restrict__ rw,
              int* __restrict__ counts, int* __restrict__ tE,
              int* __restrict__ tS, float* __restrict__ tG) {
    int wave = threadIdx.x >> 6, lane = threadIdx.x & 63;
    int t = blockIdx.x * 4 + wave;
    const float* xr = x + (size_t)t * DIM;
    float xv[16];
#pragma unroll
    for (int i = 0; i < 16; ++i) xv[i] = xr[lane + 64*i];
    float lg[NEXP];
#pragma unroll
    for (int e = 0; e < NEXP; ++e) {
        const float* wr_ = rw + e * DIM;
        float a = 0.f;
#pragma unroll
        for (int i = 0; i < 16; ++i) a += xv[i] * wr_[lane + 64*i];
        lg[e] = a;
    }
#pragma unroll
    for (int off = 32; off > 0; off >>= 1)
#pragma unroll
        for (int e = 0; e < NEXP; ++e) lg[e] += __shfl_xor(lg[e], off, 64);
    if (lane == 0) {
        float mx = lg[0];
        for (int e = 1; e < NEXP; ++e) mx = fmaxf(mx, lg[e]);
        float p[NEXP], s = 0.f;
        for (int e = 0; e < NEXP; ++e) { p[e] = expf(lg[e] - mx); s += p[e]; }
        float inv_s = 1.f / s;
        for (int e = 0; e < NEXP; ++e) p[e] *= inv_s;
        int i0 = 0;
        for (int e = 1; e < NEXP; ++e) if (p[e] > p[i0]) i0 = e;
        int i1 = (i0 == 0) ? 1 : 0;
        for (int e = 0; e < NEXP; ++e) if (e != i0 && p[e] > p[i1]) i1 = e;
        float v0 = p[i0], v1 = p[i1];
        float inv = 1.f / (v0 + v1 + 1e-9f);
        int s0 = atomicAdd(&counts[i0], 1);
        int s1 = atomicAdd(&counts[i1], 1);
        tE[2*t] = i0;  tE[2*t+1] = i1;
        tS[2*t] = s0;  tS[2*t+1] = s1;
        tG[2*t] = v0 * inv;  tG[2*t+1] = v1 * inv;
    }
}

// ---------------- exclusive scan of 128-padded counts (tiny)
__global__ void scan_k(const int* __restrict__ counts, int* __restrict__ pbase) {
    if (threadIdx.x == 0) {
        int o = 0;
        for (int e = 0; e < NEXP; ++e) { pbase[e] = o; o += ((counts[e] + 127) >> 7) << 7; }
        pbase[NEXP] = o;
    }
}

// ---------------- gather x rows (fp32) into packed bf16 rows per assignment
__global__ __launch_bounds__(256)
void gather_k(const float* __restrict__ x, const int* __restrict__ tE,
              const int* __restrict__ tS, const int* __restrict__ pbase,
              u16* __restrict__ xg) {
    int a = blockIdx.x;              // 0..8191
    int t = a >> 1, k = a & 1;
    int e = tE[2*t + k];
    int row = pbase[e] + tS[2*t + k];
    const f32x4* xr = (const f32x4*)(x + (size_t)t * DIM);
    u16x4* o = (u16x4*)(xg + (size_t)row * DIM);
    int i = threadIdx.x;             // 256 threads x 4 floats = 1024
    f32x4 v = xr[i];
    u16x4 r; r.x = f2bf(v.x); r.y = f2bf(v.y); r.z = f2bf(v.z); r.w = f2bf(v.w);
    o[i] = r;
}

// ---------------- grouped GEMM: C[row][col] = A[row][K] * Bt[col][K]  (per expert)
// m97 structure: 128x128 tile, BK=64, 4 waves, 4x4 of mfma_f32_16x16x32_bf16,
// global_load_lds width-16 staging.
template<int K, bool GELU, typename OutT>
__global__ __launch_bounds__(256)
void gemm_bt(const u16* __restrict__ A, const u16* __restrict__ BtAll,
             OutT* __restrict__ C, const int* __restrict__ counts,
             const int* __restrict__ pbase, int N) {
    int e = blockIdx.z;
    int cnt = counts[e];
    int mt = blockIdx.y;
    if (mt * 128 >= cnt) return;
    const u16* Bt = BtAll + (size_t)e * N * K;
    int row0 = pbase[e] + mt * 128;
    int col0 = blockIdx.x * 128;

    __shared__ __align__(16) u16 As[128 * 64];
    __shared__ __align__(16) u16 Bs[128 * 64];

    int tid = threadIdx.x;
    int lane = tid & 63;
    int w = tid >> 6;
    int quad = lane >> 4, m16 = lane & 15;
    int wr = (w >> 1) * 64, wc = (w & 1) * 64;
    int rsub = lane >> 3;      // 0..7: row within an 8-row staging group
    int kch  = lane & 7;       // 16B chunk within row

    f32x4 acc[4][4] = {};

    for (int kb = 0; kb < K; kb += 64) {
#pragma unroll
        for (int i = 0; i < 4; ++i) {
            int grp = w * 4 + i;               // 0..15, 8 rows each
            int r = grp * 8 + rsub;
            const u16* ga = A + (size_t)(row0 + r) * K + kb + kch * 8;
            __builtin_amdgcn_global_load_lds((gbl_uint*)ga, (lds_uint*)(As + grp * 512), 16, 0, 0);
            const u16* gb = Bt + (size_t)(col0 + r) * K + kb + kch * 8;
            __builtin_amdgcn_global_load_lds((gbl_uint*)gb, (lds_uint*)(Bs + grp * 512), 16, 0, 0);
        }
        __syncthreads();
#pragma unroll
        for (int ks = 0; ks < 64; ks += 32) {
            short8 af[4], bfr[4];
#pragma unroll
            for (int mi = 0; mi < 4; ++mi)
                af[mi] = *(const short8*)(As + (wr + mi * 16 + m16) * 64 + ks + quad * 8);
#pragma unroll
            for (int ni = 0; ni < 4; ++ni)
                bfr[ni] = *(const short8*)(Bs + (wc + ni * 16 + m16) * 64 + ks + quad * 8);
#pragma unroll
            for (int mi = 0; mi < 4; ++mi)
#pragma unroll
                for (int ni = 0; ni < 4; ++ni)
                    acc[mi][ni] = __builtin_amdgcn_mfma_f32_16x16x32_bf16(af[mi], bfr[ni], acc[mi][ni], 0, 0, 0);
        }
        __syncthreads();
    }

    // epilogue: C/D layout col=lane&15, row=quad*4+reg
#pragma unroll
    for (int mi = 0; mi < 4; ++mi) {
#pragma unroll
        for (int r = 0; r < 4; ++r) {
            int mrow = wr + mi * 16 + quad * 4 + r;
            size_t rowoff = (size_t)(row0 + mrow) * N + col0;
#pragma unroll
            for (int ni = 0; ni < 4; ++ni) {
                int ncol = wc + ni * 16 + m16;
                float v = acc[mi][ni][r];
                if (GELU) {
                    float g = 0.5f * v * (1.0f + erff(v * 0.70710678118f));
                    ((u16*)C)[rowoff + ncol] = f2bf(g);
                } else {
                    ((float*)C)[rowoff + ncol] = v;
                }
            }
        }
    }
}

// ---------------- combine: out[t] = g0*y[row0(t)] + g1*y[row1(t)]
__global__ __launch_bounds__(256)
void combine_k(const float* __restrict__ yb, const int* __restrict__ tE,
               const int* __restrict__ tS, const float* __restrict__ tG,
               const int* __restrict__ pbase, float* __restrict__ out) {
    int t = blockIdx.x;
    int e0 = tE[2*t], e1 = tE[2*t+1];
    int r0 = pbase[e0] + tS[2*t];
    int r1 = pbase[e1] + tS[2*t+1];
    float g0 = tG[2*t], g1 = tG[2*t+1];
    const f32x4* y0 = (const f32x4*)(yb + (size_t)r0 * DIM);
    const f32x4* y1 = (const f32x4*)(yb + (size_t)r1 * DIM);
    f32x4* o = (f32x4*)(out + (size_t)t * DIM);
    int i = threadIdx.x;
    o[i] = g0 * y0[i] + g1 * y1[i];
}

extern "C" void kernel_launch(void* const* d_in, const int* in_sizes, int n_in,
                              void* d_out, int out_size, void* d_ws, size_t ws_size,
                              hipStream_t stream) {
    const float* x  = (const float*)d_in[0];   // [4096,1024]
    const float* rw = (const float*)d_in[1];   // [8,1024]
    const float* w1 = (const float*)d_in[2];   // [8,1024,4096]
    const float* w2 = (const float*)d_in[3];   // [8,4096,1024]
    float* out = (float*)d_out;

    char* ws = (char*)d_ws;
    // layout (bytes):
    u16* w1t = (u16*)(ws + 0);              // bf16 [E][H][D]   67,108,864
    u16* w2t = (u16*)(ws + 67108864ull);    // bf16 [E][D][H]   67,108,864 -> 134,217,728
    u16* xg  = (u16*)(ws + 134217728ull);   // bf16 [9216][D]   18,874,368 -> 153,092,096
    u16* hb  = (u16*)(ws + 153092096ull);   // bf16 [9216][H]   75,497,472 -> 228,589,568
    float* yb = (float*)(ws + 0);           // f32 [9216][D] aliases w1t (used only after fc1 done)
    int* ctrl   = (int*)(ws + 228589568ull);
    int* counts = ctrl;            // 8
    int* pbase  = ctrl + 8;        // 9
    int* tE     = ctrl + 32;       // 8192
    int* tS     = ctrl + 32 + 8192;
    float* tG   = (float*)(ctrl + 32 + 16384);

    hipMemsetAsync(counts, 0, 8 * sizeof(int), stream);

    transpose_cast<<<dim3(128, 32, NEXP), dim3(32, 8), 0, stream>>>(w1, w1t, DIM, HID);
    transpose_cast<<<dim3(32, 128, NEXP), dim3(32, 8), 0, stream>>>(w2, w2t, HID, DIM);
    router_k<<<T_TOK / 4, 256, 0, stream>>>(x, rw, counts, tE, tS, tG);
    scan_k<<<1, 64, 0, stream>>>(counts, pbase);
    gather_k<<<T_TOK * 2, 256, 0, stream>>>(x, tE, tS, pbase, xg);
    // fc1 + gelu: [rows x 1024] @ [1024 x 4096] -> hb
    gemm_bt<DIM, true, u16><<<dim3(HID / 128, 32, NEXP), 256, 0, stream>>>(xg, w1t, hb, counts, pbase, HID);
    // fc2: [rows x 4096] @ [4096 x 1024] -> yb
    gemm_bt<HID, false, float><<<dim3(DIM / 128, 32, NEXP), 256, 0, stream>>>(hb, w2t, yb, counts, pbase, DIM);
    combine_k<<<T_TOK, 256, 0, stream>>>(yb, tE, tS, tG, pbase, out);
}

// Round 2
// 735.886 us; speedup vs baseline: 1.0584x; 1.0584x over previous
//
#include <hip/hip_runtime.h>

// Problem constants: B=2, S=2048 -> T=4096 tokens; D=1024, H=4096, E=8, top-2.
#define T_TOK 4096
#define DIM   1024
#define HID   4096
#define NEXP  8
#define MAXROWS 9216

typedef unsigned short u16;
typedef __attribute__((ext_vector_type(8))) short short8;   // 8 bf16 (4 VGPRs) MFMA frag
typedef __attribute__((ext_vector_type(4))) float f32x4;
typedef __attribute__((ext_vector_type(4))) unsigned short u16x4;
typedef __attribute__((ext_vector_type(8))) unsigned short u16x8;

typedef __attribute__((address_space(3))) unsigned int lds_uint;
typedef const __attribute__((address_space(1))) unsigned int gbl_uint;

__device__ __forceinline__ u16 f2bf(float f) {
    union { float f; unsigned int u; } v; v.f = f;
    unsigned int r = v.u + 0x7fffu + ((v.u >> 16) & 1u);   // RNE
    return (u16)(r >> 16);
}

// fast gelu (tanh form): max |err| vs exact erf-gelu ~3e-4, well under budget
__device__ __forceinline__ float gelu_f(float v) {
    float u = 1.5957691216f * (v + 0.044715f * v * v * v);   // 2*0.7978845608*(...)
    float s = 1.0f / (1.0f + __expf(-u));                    // sigmoid(2u') == 0.5*(1+tanh(u'))
    return v * s;
}

// ---------------- transpose + cast fp32 [R][C] -> bf16 [C][R], per expert (blockIdx.z)
// 64x64 tile, 256 threads; coalesced f32x4 reads, coalesced u16x4 writes.
__global__ __launch_bounds__(256)
void transpose_cast(const float* __restrict__ in, u16* __restrict__ out, int R, int C) {
    __shared__ u16 t[64 * 68];    // stride 68 u16 (136 B) keeps 8B alignment, breaks pow2 banks
    size_t mo = (size_t)blockIdx.z * R * C;
    const float* ip = in + mo;
    u16* op = out + mo;
    int c0 = blockIdx.x * 64, r0 = blockIdx.y * 64;
    int tid = threadIdx.x;
#pragma unroll
    for (int j = 0; j < 4; ++j) {
        int id = tid + 256 * j;
        int r = id >> 4, cc = id & 15;
        f32x4 v = *(const f32x4*)(ip + (size_t)(r0 + r) * C + c0 + 4 * cc);
        u16x4 w; w.x = f2bf(v.x); w.y = f2bf(v.y); w.z = f2bf(v.z); w.w = f2bf(v.w);
        *(u16x4*)(t + r * 68 + 4 * cc) = w;
    }
    __syncthreads();
#pragma unroll
    for (int j = 0; j < 4; ++j) {
        int id = tid + 256 * j;
        int c = id >> 4, rj = id & 15;
        u16x4 o;
        o.x = t[(4 * rj + 0) * 68 + c];
        o.y = t[(4 * rj + 1) * 68 + c];
        o.z = t[(4 * rj + 2) * 68 + c];
        o.w = t[(4 * rj + 3) * 68 + c];
        *(u16x4*)(op + (size_t)(c0 + c) * R + r0 + 4 * rj) = o;
    }
}

// ---------------- router: logits -> softmax -> top2 -> renormalized gates
__global__ __launch_bounds__(256)
void router_k(const float* __restrict__ x, const float* __restrict__ rw,
              int* __restrict__ counts, int* __restrict__ tE,
              int* __restrict__ tS, float* __restrict__ tG) {
    int wave = threadIdx.x >> 6, lane = threadIdx.x & 63;
    int t = blockIdx.x * 4 + wave;
    const float* xr = x + (size_t)t * DIM;
    float xv[16];
#pragma unroll
    for (int i = 0; i < 16; ++i) xv[i] = xr[lane + 64*i];
    float lg[NEXP];
#pragma unroll
    for (int e = 0; e < NEXP; ++e) {
        const float* wr_ = rw + e * DIM;
        float a = 0.f;
#pragma unroll
        for (int i = 0; i < 16; ++i) a += xv[i] * wr_[lane + 64*i];
        lg[e] = a;
    }
#pragma unroll
    for (int off = 32; off > 0; off >>= 1)
#pragma unroll
        for (int e = 0; e < NEXP; ++e) lg[e] += __shfl_xor(lg[e], off, 64);
    if (lane == 0) {
        float mx = lg[0];
        for (int e = 1; e < NEXP; ++e) mx = fmaxf(mx, lg[e]);
        float p[NEXP], s = 0.f;
        for (int e = 0; e < NEXP; ++e) { p[e] = expf(lg[e] - mx); s += p[e]; }
        float inv_s = 1.f / s;
        for (int e = 0; e < NEXP; ++e) p[e] *= inv_s;
        int i0 = 0;
        for (int e = 1; e < NEXP; ++e) if (p[e] > p[i0]) i0 = e;
        int i1 = (i0 == 0) ? 1 : 0;
        for (int e = 0; e < NEXP; ++e) if (e != i0 && p[e] > p[i1]) i1 = e;
        float v0 = p[i0], v1 = p[i1];
        float inv = 1.f / (v0 + v1 + 1e-9f);
        int s0 = atomicAdd(&counts[i0], 1);
        int s1 = atomicAdd(&counts[i1], 1);
        tE[2*t] = i0;  tE[2*t+1] = i1;
        tS[2*t] = s0;  tS[2*t+1] = s1;
        tG[2*t] = v0 * inv;  tG[2*t+1] = v1 * inv;
    }
}

// ---------------- exclusive scan of 128-padded counts (tiny)
__global__ void scan_k(const int* __restrict__ counts, int* __restrict__ pbase) {
    if (threadIdx.x == 0) {
        int o = 0;
        for (int e = 0; e < NEXP; ++e) { pbase[e] = o; o += ((counts[e] + 127) >> 7) << 7; }
        pbase[NEXP] = o;
    }
}

// ---------------- gather x rows (fp32) into packed bf16 rows per assignment
__global__ __launch_bounds__(256)
void gather_k(const float* __restrict__ x, const int* __restrict__ tE,
              const int* __restrict__ tS, const int* __restrict__ pbase,
              u16* __restrict__ xg) {
    int a = blockIdx.x;              // 0..8191
    int t = a >> 1, k = a & 1;
    int e = tE[2*t + k];
    int row = pbase[e] + tS[2*t + k];
    const f32x4* xr = (const f32x4*)(x + (size_t)t * DIM);
    u16x4* o = (u16x4*)(xg + (size_t)row * DIM);
    int i = threadIdx.x;             // 256 threads x 4 floats = 1024
    f32x4 v = xr[i];
    u16x4 r; r.x = f2bf(v.x); r.y = f2bf(v.y); r.z = f2bf(v.z); r.w = f2bf(v.w);
    o[i] = r;
}

// ---------------- grouped GEMM: C[row][col] = A[row][K_sub] * Bt[col][K_sub]  (per expert)
// m97 structure: 128x128 tile, BK=64, 4 waves, 4x4 of mfma_f32_16x16x32_bf16,
// global_load_lds width-16 staging. KSPLIT: blockIdx.z = expert*KSPLIT + kslice,
// each kslice writes its own C buffer (C + ks*cstride), reduced downstream.
template<int K, int KSPLIT, bool GELU, typename OutT>
__global__ __launch_bounds__(256)
void gemm_bt(const u16* __restrict__ A, const u16* __restrict__ BtAll,
             OutT* __restrict__ C, const int* __restrict__ counts,
             const int* __restrict__ pbase, int N, size_t cstride) {
    int e  = blockIdx.z / KSPLIT;
    int ks = blockIdx.z % KSPLIT;
    int cnt = counts[e];
    int mt = blockIdx.y;
    if (mt * 128 >= cnt) return;
    const u16* Bt = BtAll + (size_t)e * N * K;
    OutT* Cp = C + (size_t)ks * cstride;
    int row0 = pbase[e] + mt * 128;
    int col0 = blockIdx.x * 128;
    const int kb0 = ks * (K / KSPLIT);
    const int kb1 = kb0 + (K / KSPLIT);

    __shared__ __align__(16) u16 smem[128 * 128];   // As = [0,8K), Bs = [8K,16K); epilogue reuses all 32 KB
    u16* As = smem;
    u16* Bs = smem + 128 * 64;

    int tid = threadIdx.x;
    int lane = tid & 63;
    int w = tid >> 6;
    int quad = lane >> 4, m16 = lane & 15;
    int wr = (w >> 1) * 64, wc = (w & 1) * 64;
    int rsub = lane >> 3;      // 0..7: row within an 8-row staging group
    int kch  = lane & 7;       // 16B chunk within row

    f32x4 acc[4][4] = {};

    for (int kb = kb0; kb < kb1; kb += 64) {
#pragma unroll
        for (int i = 0; i < 4; ++i) {
            int grp = w * 4 + i;               // 0..15, 8 rows each
            int r = grp * 8 + rsub;
            const u16* ga = A + (size_t)(row0 + r) * K + kb + kch * 8;
            __builtin_amdgcn_global_load_lds((gbl_uint*)ga, (lds_uint*)(As + grp * 512), 16, 0, 0);
            const u16* gb = Bt + (size_t)(col0 + r) * K + kb + kch * 8;
            __builtin_amdgcn_global_load_lds((gbl_uint*)gb, (lds_uint*)(Bs + grp * 512), 16, 0, 0);
        }
        __syncthreads();
#pragma unroll
        for (int ks2 = 0; ks2 < 64; ks2 += 32) {
            short8 af[4], bfr[4];
#pragma unroll
            for (int mi = 0; mi < 4; ++mi)
                af[mi] = *(const short8*)(As + (wr + mi * 16 + m16) * 64 + ks2 + quad * 8);
#pragma unroll
            for (int ni = 0; ni < 4; ++ni)
                bfr[ni] = *(const short8*)(Bs + (wc + ni * 16 + m16) * 64 + ks2 + quad * 8);
#pragma unroll
            for (int mi = 0; mi < 4; ++mi)
#pragma unroll
                for (int ni = 0; ni < 4; ++ni)
                    acc[mi][ni] = __builtin_amdgcn_mfma_f32_16x16x32_bf16(af[mi], bfr[ni], acc[mi][ni], 0, 0, 0);
        }
        __syncthreads();
    }

    // epilogue: C/D layout col=lane&15, row=quad*4+reg
    if (GELU) {
        // stage bf16 tile in LDS (XOR-swizzled 16B chunks), then coalesced u16x8 stores
#pragma unroll
        for (int mi = 0; mi < 4; ++mi) {
#pragma unroll
            for (int r = 0; r < 4; ++r) {
                int row = wr + mi * 16 + quad * 4 + r;
#pragma unroll
                for (int ni = 0; ni < 4; ++ni) {
                    int col = wc + ni * 16 + m16;
                    int c16 = col >> 3, w8 = col & 7;
                    smem[row * 128 + (((c16 ^ (row & 15)) << 3) | w8)] = f2bf(gelu_f(acc[mi][ni][r]));
                }
            }
        }
        __syncthreads();
#pragma unroll
        for (int j = 0; j < 8; ++j) {
            int id = tid + 256 * j;
            int row = id >> 4, c16 = id & 15;
            u16x8 val = *(const u16x8*)(smem + row * 128 + ((c16 ^ (row & 15)) << 3));
            *(u16x8*)((u16*)Cp + (size_t)(row0 + row) * N + col0 + c16 * 8) = val;
        }
    } else {
#pragma unroll
        for (int mi = 0; mi < 4; ++mi) {
#pragma unroll
            for (int r = 0; r < 4; ++r) {
                int mrow = wr + mi * 16 + quad * 4 + r;
                size_t rowoff = (size_t)(row0 + mrow) * N + col0;
#pragma unroll
                for (int ni = 0; ni < 4; ++ni) {
                    int ncol = wc + ni * 16 + m16;
                    ((float*)Cp)[rowoff + ncol] = acc[mi][ni][r];
                }
            }
        }
    }
}

// ---------------- combine: out[t] = g0*(p0+p1)[row0(t)] + g1*(p0+p1)[row1(t)]
__global__ __launch_bounds__(256)
void combine_k(const float* __restrict__ p0, const float* __restrict__ p1,
               const int* __restrict__ tE, const int* __restrict__ tS,
               const float* __restrict__ tG, const int* __restrict__ pbase,
               float* __restrict__ out) {
    int t = blockIdx.x;
    int e0 = tE[2*t], e1 = tE[2*t+1];
    int r0 = pbase[e0] + tS[2*t];
    int r1 = pbase[e1] + tS[2*t+1];
    float g0 = tG[2*t], g1 = tG[2*t+1];
    int i = threadIdx.x;
    f32x4 a0 = ((const f32x4*)(p0 + (size_t)r0 * DIM))[i];
    f32x4 b0 = ((const f32x4*)(p1 + (size_t)r0 * DIM))[i];
    f32x4 a1 = ((const f32x4*)(p0 + (size_t)r1 * DIM))[i];
    f32x4 b1 = ((const f32x4*)(p1 + (size_t)r1 * DIM))[i];
    f32x4* o = (f32x4*)(out + (size_t)t * DIM);
    o[i] = g0 * (a0 + b0) + g1 * (a1 + b1);
}

extern "C" void kernel_launch(void* const* d_in, const int* in_sizes, int n_in,
                              void* d_out, int out_size, void* d_ws, size_t ws_size,
                              hipStream_t stream) {
    const float* x  = (const float*)d_in[0];   // [4096,1024]
    const float* rw = (const float*)d_in[1];   // [8,1024]
    const float* w1 = (const float*)d_in[2];   // [8,1024,4096]
    const float* w2 = (const float*)d_in[3];   // [8,4096,1024]
    float* out = (float*)d_out;

    char* ws = (char*)d_ws;
    // layout (bytes):
    u16* w1t = (u16*)(ws + 0);                 // bf16 [E][H][D]   67,108,864
    u16* xg  = (u16*)(ws + 67108864ull);       // bf16 [9216][D]   18,874,368 -> 85,983,232
    u16* w2t = (u16*)(ws + 85983232ull);       // bf16 [E][D][H]   67,108,864 -> 153,092,096
    u16* hb  = (u16*)(ws + 153092096ull);      // bf16 [9216][H]   75,497,472 -> 228,589,568
    // fc2 split-K partials alias w1t+xg (dead after fc1): 2 x 37,748,736 = 75,497,472 <= 85,983,232
    float* p0 = (float*)(ws + 0);
    float* p1 = (float*)(ws + 37748736ull);
    int* ctrl   = (int*)(ws + 228589568ull);
    int* counts = ctrl;            // 8
    int* pbase  = ctrl + 8;        // 9
    int* tE     = ctrl + 32;       // 8192
    int* tS     = ctrl + 32 + 8192;
    float* tG   = (float*)(ctrl + 32 + 16384);

    hipMemsetAsync(counts, 0, 8 * sizeof(int), stream);

    // w1 [D=1024][H=4096] -> w1t [H][D];  w2 [H=4096][D=1024] -> w2t [D][H]
    transpose_cast<<<dim3(HID / 64, DIM / 64, NEXP), 256, 0, stream>>>(w1, w1t, DIM, HID);
    transpose_cast<<<dim3(DIM / 64, HID / 64, NEXP), 256, 0, stream>>>(w2, w2t, HID, DIM);
    router_k<<<T_TOK / 4, 256, 0, stream>>>(x, rw, counts, tE, tS, tG);
    scan_k<<<1, 64, 0, stream>>>(counts, pbase);
    gather_k<<<T_TOK * 2, 256, 0, stream>>>(x, tE, tS, pbase, xg);
    // fc1 + gelu: [rows x 1024] @ [1024 x 4096] -> hb (bf16)
    gemm_bt<DIM, 1, true, u16><<<dim3(HID / 128, 32, NEXP), 256, 0, stream>>>(
        xg, w1t, hb, counts, pbase, HID, 0);
    // fc2 split-K=2: [rows x 4096] @ [4096 x 1024] -> p0/p1 (f32)
    gemm_bt<HID, 2, false, float><<<dim3(DIM / 128, 32, NEXP * 2), 256, 0, stream>>>(
        hb, w2t, p0, counts, pbase, DIM, (size_t)MAXROWS * DIM);
    combine_k<<<T_TOK, 256, 0, stream>>>(p0, p1, tE, tS, tG, pbase, out);
}

// Round 3
// 683.436 us; speedup vs baseline: 1.1396x; 1.0767x over previous
//
#include <hip/hip_runtime.h>

// Problem constants: B=2, S=2048 -> T=4096 tokens; D=1024, H=4096, E=8, top-2.
#define T_TOK 4096
#define DIM   1024
#define HID   4096
#define NEXP  8
#define MAXROWS 9216

typedef unsigned short u16;
typedef __attribute__((ext_vector_type(8))) short short8;   // 8 bf16 (4 VGPRs) MFMA frag
typedef __attribute__((ext_vector_type(4))) float f32x4;
typedef __attribute__((ext_vector_type(4))) unsigned short u16x4;
typedef __attribute__((ext_vector_type(8))) unsigned short u16x8;

typedef __attribute__((address_space(3))) unsigned int lds_uint;
typedef const __attribute__((address_space(1))) unsigned int gbl_uint;

__device__ __forceinline__ u16 f2bf(float f) {
    union { float f; unsigned int u; } v; v.f = f;
    unsigned int r = v.u + 0x7fffu + ((v.u >> 16) & 1u);   // RNE
    return (u16)(r >> 16);
}

// fast gelu (tanh form): max |err| vs exact erf-gelu ~3e-4, well under budget
__device__ __forceinline__ float gelu_f(float v) {
    float u = 1.5957691216f * (v + 0.044715f * v * v * v);   // 2*0.7978845608*(...)
    float s = 1.0f / (1.0f + __expf(-u));                    // sigmoid(2u') == 0.5*(1+tanh(u'))
    return v * s;
}

// ---------------- transpose + cast fp32 [R][C] -> bf16 [C][R], per expert (blockIdx.z)
// 64x64 tile, 256 threads; coalesced f32x4 reads, coalesced u16x4 writes.
__global__ __launch_bounds__(256)
void transpose_cast(const float* __restrict__ in, u16* __restrict__ out, int R, int C) {
    __shared__ u16 t[64 * 68];    // stride 68 u16 (136 B) keeps 8B alignment, breaks pow2 banks
    size_t mo = (size_t)blockIdx.z * R * C;
    const float* ip = in + mo;
    u16* op = out + mo;
    int c0 = blockIdx.x * 64, r0 = blockIdx.y * 64;
    int tid = threadIdx.x;
#pragma unroll
    for (int j = 0; j < 4; ++j) {
        int id = tid + 256 * j;
        int r = id >> 4, cc = id & 15;
        f32x4 v = *(const f32x4*)(ip + (size_t)(r0 + r) * C + c0 + 4 * cc);
        u16x4 w; w.x = f2bf(v.x); w.y = f2bf(v.y); w.z = f2bf(v.z); w.w = f2bf(v.w);
        *(u16x4*)(t + r * 68 + 4 * cc) = w;
    }
    __syncthreads();
#pragma unroll
    for (int j = 0; j < 4; ++j) {
        int id = tid + 256 * j;
        int c = id >> 4, rj = id & 15;
        u16x4 o;
        o.x = t[(4 * rj + 0) * 68 + c];
        o.y = t[(4 * rj + 1) * 68 + c];
        o.z = t[(4 * rj + 2) * 68 + c];
        o.w = t[(4 * rj + 3) * 68 + c];
        *(u16x4*)(op + (size_t)(c0 + c) * R + r0 + 4 * rj) = o;
    }
}

// ---------------- router: logits -> softmax -> top2 -> renormalized gates
__global__ __launch_bounds__(256)
void router_k(const float* __restrict__ x, const float* __restrict__ rw,
              int* __restrict__ counts, int* __restrict__ tE,
              int* __restrict__ tS, float* __restrict__ tG) {
    int wave = threadIdx.x >> 6, lane = threadIdx.x & 63;
    int t = blockIdx.x * 4 + wave;
    const float* xr = x + (size_t)t * DIM;
    float xv[16];
#pragma unroll
    for (int i = 0; i < 16; ++i) xv[i] = xr[lane + 64*i];
    float lg[NEXP];
#pragma unroll
    for (int e = 0; e < NEXP; ++e) {
        const float* wr_ = rw + e * DIM;
        float a = 0.f;
#pragma unroll
        for (int i = 0; i < 16; ++i) a += xv[i] * wr_[lane + 64*i];
        lg[e] = a;
    }
#pragma unroll
    for (int off = 32; off > 0; off >>= 1)
#pragma unroll
        for (int e = 0; e < NEXP; ++e) lg[e] += __shfl_xor(lg[e], off, 64);
    if (lane == 0) {
        float mx = lg[0];
        for (int e = 1; e < NEXP; ++e) mx = fmaxf(mx, lg[e]);
        float p[NEXP], s = 0.f;
        for (int e = 0; e < NEXP; ++e) { p[e] = expf(lg[e] - mx); s += p[e]; }
        float inv_s = 1.f / s;
        for (int e = 0; e < NEXP; ++e) p[e] *= inv_s;
        int i0 = 0;
        for (int e = 1; e < NEXP; ++e) if (p[e] > p[i0]) i0 = e;
        int i1 = (i0 == 0) ? 1 : 0;
        for (int e = 0; e < NEXP; ++e) if (e != i0 && p[e] > p[i1]) i1 = e;
        float v0 = p[i0], v1 = p[i1];
        float inv = 1.f / (v0 + v1 + 1e-9f);
        int s0 = atomicAdd(&counts[i0], 1);
        int s1 = atomicAdd(&counts[i1], 1);
        tE[2*t] = i0;  tE[2*t+1] = i1;
        tS[2*t] = s0;  tS[2*t+1] = s1;
        tG[2*t] = v0 * inv;  tG[2*t+1] = v1 * inv;
    }
}

// ---------------- exclusive scan of 128-padded counts (tiny)
__global__ void scan_k(const int* __restrict__ counts, int* __restrict__ pbase) {
    if (threadIdx.x == 0) {
        int o = 0;
        for (int e = 0; e < NEXP; ++e) { pbase[e] = o; o += ((counts[e] + 127) >> 7) << 7; }
        pbase[NEXP] = o;
    }
}

// ---------------- gather x rows (fp32) into packed bf16 rows per assignment
__global__ __launch_bounds__(256)
void gather_k(const float* __restrict__ x, const int* __restrict__ tE,
              const int* __restrict__ tS, const int* __restrict__ pbase,
              u16* __restrict__ xg) {
    int a = blockIdx.x;              // 0..8191
    int t = a >> 1, k = a & 1;
    int e = tE[2*t + k];
    int row = pbase[e] + tS[2*t + k];
    const f32x4* xr = (const f32x4*)(x + (size_t)t * DIM);
    u16x4* o = (u16x4*)(xg + (size_t)row * DIM);
    int i = threadIdx.x;             // 256 threads x 4 floats = 1024
    f32x4 v = xr[i];
    u16x4 r; r.x = f2bf(v.x); r.y = f2bf(v.y); r.z = f2bf(v.z); r.w = f2bf(v.w);
    o[i] = r;
}

// ---------------- grouped GEMM: C[row][col] = A[row][K_sub] * Bt[col][K_sub]  (per expert)
// m97 structure: 128x128 tile, BK=64, 4 waves, 4x4 of mfma_f32_16x16x32_bf16,
// global_load_lds width-16 staging. KSPLIT: blockIdx.z = expert*KSPLIT + kslice.
// XOR-swizzled LDS: row r position p (16B units) holds global k-chunk p^(r&7),
// arranged by having lane (rsub,kch) fetch global chunk kch^rsub. Fragment
// ds_read_b128 then XORs the position back -> lanes spread over all 8 bank
// groups (2-way aliasing = free) instead of 16-way conflicts at stride 128B.
template<int K, int KSPLIT, bool GELU, typename OutT>
__global__ __launch_bounds__(256)
void gemm_bt(const u16* __restrict__ A, const u16* __restrict__ BtAll,
             OutT* __restrict__ C, const int* __restrict__ counts,
             const int* __restrict__ pbase, int N, size_t cstride) {
    int e  = blockIdx.z / KSPLIT;
    int ks = blockIdx.z % KSPLIT;
    int cnt = counts[e];
    int mt = blockIdx.y;
    if (mt * 128 >= cnt) return;
    const u16* Bt = BtAll + (size_t)e * N * K;
    OutT* Cp = C + (size_t)ks * cstride;
    int row0 = pbase[e] + mt * 128;
    int col0 = blockIdx.x * 128;
    const int kb0 = ks * (K / KSPLIT);
    const int kb1 = kb0 + (K / KSPLIT);

    __shared__ __align__(16) u16 smem[128 * 128];   // As = [0,8K), Bs = [8K,16K); epilogue reuses all 32 KB
    u16* As = smem;
    u16* Bs = smem + 128 * 64;

    int tid = threadIdx.x;
    int lane = tid & 63;
    int w = tid >> 6;
    int quad = lane >> 4, m16 = lane & 15;
    int wr = (w >> 1) * 64, wc = (w & 1) * 64;
    int rsub = lane >> 3;      // 0..7: row within an 8-row staging group
    int kch  = lane & 7;       // 16B chunk within row (LDS slot)
    int kchs = kch ^ rsub;     // swizzled GLOBAL chunk fetched into that slot

    f32x4 acc[4][4] = {};

    for (int kb = kb0; kb < kb1; kb += 64) {
#pragma unroll
        for (int i = 0; i < 4; ++i) {
            int grp = w * 4 + i;               // 0..15, 8 rows each
            int r = grp * 8 + rsub;
            const u16* ga = A + (size_t)(row0 + r) * K + kb + kchs * 8;
            __builtin_amdgcn_global_load_lds((gbl_uint*)ga, (lds_uint*)(As + grp * 512), 16, 0, 0);
            const u16* gb = Bt + (size_t)(col0 + r) * K + kb + kchs * 8;
            __builtin_amdgcn_global_load_lds((gbl_uint*)gb, (lds_uint*)(Bs + grp * 512), 16, 0, 0);
        }
        __syncthreads();
#pragma unroll
        for (int ks2 = 0; ks2 < 64; ks2 += 32) {
            int cbase = (ks2 >> 3) + quad;     // global k-chunk index this frag needs
            short8 af[4], bfr[4];
#pragma unroll
            for (int mi = 0; mi < 4; ++mi) {
                int ra = wr + mi * 16 + m16;
                af[mi] = *(const short8*)(As + ra * 64 + ((cbase ^ (ra & 7)) << 3));
            }
#pragma unroll
            for (int ni = 0; ni < 4; ++ni) {
                int rb = wc + ni * 16 + m16;
                bfr[ni] = *(const short8*)(Bs + rb * 64 + ((cbase ^ (rb & 7)) << 3));
            }
#pragma unroll
            for (int mi = 0; mi < 4; ++mi)
#pragma unroll
                for (int ni = 0; ni < 4; ++ni)
                    acc[mi][ni] = __builtin_amdgcn_mfma_f32_16x16x32_bf16(af[mi], bfr[ni], acc[mi][ni], 0, 0, 0);
        }
        __syncthreads();
    }

    // epilogue: C/D layout col=lane&15, row=quad*4+reg
    if (GELU) {
        // stage bf16 tile in LDS (XOR-swizzled 16B chunks), then coalesced u16x8 stores
#pragma unroll
        for (int mi = 0; mi < 4; ++mi) {
#pragma unroll
            for (int r = 0; r < 4; ++r) {
                int row = wr + mi * 16 + quad * 4 + r;
#pragma unroll
                for (int ni = 0; ni < 4; ++ni) {
                    int col = wc + ni * 16 + m16;
                    int c16 = col >> 3, w8 = col & 7;
                    smem[row * 128 + (((c16 ^ (row & 15)) << 3) | w8)] = f2bf(gelu_f(acc[mi][ni][r]));
                }
            }
        }
        __syncthreads();
#pragma unroll
        for (int j = 0; j < 8; ++j) {
            int id = tid + 256 * j;
            int row = id >> 4, c16 = id & 15;
            u16x8 val = *(const u16x8*)(smem + row * 128 + ((c16 ^ (row & 15)) << 3));
            *(u16x8*)((u16*)Cp + (size_t)(row0 + row) * N + col0 + c16 * 8) = val;
        }
    } else {
#pragma unroll
        for (int mi = 0; mi < 4; ++mi) {
#pragma unroll
            for (int r = 0; r < 4; ++r) {
                int mrow = wr + mi * 16 + quad * 4 + r;
                size_t rowoff = (size_t)(row0 + mrow) * N + col0;
#pragma unroll
                for (int ni = 0; ni < 4; ++ni) {
                    int ncol = wc + ni * 16 + m16;
                    ((float*)Cp)[rowoff + ncol] = acc[mi][ni][r];
                }
            }
        }
    }
}

// ---------------- combine: out[t] = g0*(p0+p1)[row0(t)] + g1*(p0+p1)[row1(t)]
__global__ __launch_bounds__(256)
void combine_k(const float* __restrict__ p0, const float* __restrict__ p1,
               const int* __restrict__ tE, const int* __restrict__ tS,
               const float* __restrict__ tG, const int* __restrict__ pbase,
               float* __restrict__ out) {
    int t = blockIdx.x;
    int e0 = tE[2*t], e1 = tE[2*t+1];
    int r0 = pbase[e0] + tS[2*t];
    int r1 = pbase[e1] + tS[2*t+1];
    float g0 = tG[2*t], g1 = tG[2*t+1];
    int i = threadIdx.x;
    f32x4 a0 = ((const f32x4*)(p0 + (size_t)r0 * DIM))[i];
    f32x4 b0 = ((const f32x4*)(p1 + (size_t)r0 * DIM))[i];
    f32x4 a1 = ((const f32x4*)(p0 + (size_t)r1 * DIM))[i];
    f32x4 b1 = ((const f32x4*)(p1 + (size_t)r1 * DIM))[i];
    f32x4* o = (f32x4*)(out + (size_t)t * DIM);
    o[i] = g0 * (a0 + b0) + g1 * (a1 + b1);
}

extern "C" void kernel_launch(void* const* d_in, const int* in_sizes, int n_in,
                              void* d_out, int out_size, void* d_ws, size_t ws_size,
                              hipStream_t stream) {
    const float* x  = (const float*)d_in[0];   // [4096,1024]
    const float* rw = (const float*)d_in[1];   // [8,1024]
    const float* w1 = (const float*)d_in[2];   // [8,1024,4096]
    const float* w2 = (const float*)d_in[3];   // [8,4096,1024]
    float* out = (float*)d_out;

    char* ws = (char*)d_ws;
    // layout (bytes):
    u16* w1t = (u16*)(ws + 0);                 // bf16 [E][H][D]   67,108,864
    u16* xg  = (u16*)(ws + 67108864ull);       // bf16 [9216][D]   18,874,368 -> 85,983,232
    u16* w2t = (u16*)(ws + 85983232ull);       // bf16 [E][D][H]   67,108,864 -> 153,092,096
    u16* hb  = (u16*)(ws + 153092096ull);      // bf16 [9216][H]   75,497,472 -> 228,589,568
    // fc2 split-K partials alias w1t+xg (dead after fc1): 2 x 37,748,736 = 75,497,472 <= 85,983,232
    float* p0 = (float*)(ws + 0);
    float* p1 = (float*)(ws + 37748736ull);
    int* ctrl   = (int*)(ws + 228589568ull);
    int* counts = ctrl;            // 8
    int* pbase  = ctrl + 8;        // 9
    int* tE     = ctrl + 32;       // 8192
    int* tS     = ctrl + 32 + 8192;
    float* tG   = (float*)(ctrl + 32 + 16384);

    hipMemsetAsync(counts, 0, 8 * sizeof(int), stream);

    // w1 [D=1024][H=4096] -> w1t [H][D];  w2 [H=4096][D=1024] -> w2t [D][H]
    transpose_cast<<<dim3(HID / 64, DIM / 64, NEXP), 256, 0, stream>>>(w1, w1t, DIM, HID);
    transpose_cast<<<dim3(DIM / 64, HID / 64, NEXP), 256, 0, stream>>>(w2, w2t, HID, DIM);
    router_k<<<T_TOK / 4, 256, 0, stream>>>(x, rw, counts, tE, tS, tG);
    scan_k<<<1, 64, 0, stream>>>(counts, pbase);
    gather_k<<<T_TOK * 2, 256, 0, stream>>>(x, tE, tS, pbase, xg);
    // fc1 + gelu: [rows x 1024] @ [1024 x 4096] -> hb (bf16)
    gemm_bt<DIM, 1, true, u16><<<dim3(HID / 128, 32, NEXP), 256, 0, stream>>>(
        xg, w1t, hb, counts, pbase, HID, 0);
    // fc2 split-K=2: [rows x 4096] @ [4096 x 1024] -> p0/p1 (f32)
    gemm_bt<HID, 2, false, float><<<dim3(DIM / 128, 32, NEXP * 2), 256, 0, stream>>>(
        hb, w2t, p0, counts, pbase, DIM, (size_t)MAXROWS * DIM);
    combine_k<<<T_TOK, 256, 0, stream>>>(p0, p1, tE, tS, tG, pbase, out);
}

// Round 4
// 671.753 us; speedup vs baseline: 1.1594x; 1.0174x over previous
//
#include <hip/hip_runtime.h>

// Problem constants: B=2, S=2048 -> T=4096 tokens; D=1024, H=4096, E=8, top-2.
#define T_TOK 4096
#define DIM   1024
#define HID   4096
#define NEXP  8
#define MAXROWS 9216

typedef unsigned short u16;
typedef __attribute__((ext_vector_type(8))) short short8;   // 8 bf16 (4 VGPRs) MFMA frag
typedef __attribute__((ext_vector_type(4))) float f32x4;
typedef __attribute__((ext_vector_type(4))) unsigned short u16x4;
typedef __attribute__((ext_vector_type(8))) unsigned short u16x8;

typedef __attribute__((address_space(3))) unsigned int lds_uint;
typedef const __attribute__((address_space(1))) unsigned int gbl_uint;

__device__ __forceinline__ u16 f2bf(float f) {
    union { float f; unsigned int u; } v; v.f = f;
    unsigned int r = v.u + 0x7fffu + ((v.u >> 16) & 1u);   // RNE
    return (u16)(r >> 16);
}

// fast gelu (tanh form): max |err| vs exact erf-gelu ~3e-4, well under budget
__device__ __forceinline__ float gelu_f(float v) {
    float u = 1.5957691216f * (v + 0.044715f * v * v * v);   // 2*0.7978845608*(...)
    float s = 1.0f / (1.0f + __expf(-u));                    // sigmoid(2u') == 0.5*(1+tanh(u'))
    return v * s;
}

// ---------------- fused transpose+cast for BOTH weights; also zeroes counts.
// fp32 [R][C] -> bf16 [C][R] per expert. blockIdx.x in [0,16384):
// first 8192 blocks: w1 (R=1024,C=4096); rest: w2 (R=4096,C=1024).
__global__ __launch_bounds__(256)
void transpose_cast2(const float* __restrict__ w1, u16* __restrict__ w1t,
                     const float* __restrict__ w2, u16* __restrict__ w2t,
                     int* __restrict__ counts) {
    int b = blockIdx.x;
    if (b == 0 && threadIdx.x < NEXP) counts[threadIdx.x] = 0;
    const float* in; u16* out; int R, C, bx, by, e;
    if (b < 8192) {
        e = b >> 10; int t = b & 1023; bx = t & 63; by = t >> 6;   // 64 x, 16 y
        in = w1; out = w1t; R = DIM; C = HID;
    } else {
        b -= 8192;
        e = b >> 10; int t = b & 1023; bx = t & 15; by = t >> 4;   // 16 x, 64 y
        in = w2; out = w2t; R = HID; C = DIM;
    }
    __shared__ u16 t[64 * 68];    // stride 68 u16 keeps 8B alignment, breaks pow2 banks
    size_t mo = (size_t)e * DIM * HID;
    const float* ip = in + mo;
    u16* op = out + mo;
    int c0 = bx * 64, r0 = by * 64;
    int tid = threadIdx.x;
#pragma unroll
    for (int j = 0; j < 4; ++j) {
        int id = tid + 256 * j;
        int r = id >> 4, cc = id & 15;
        f32x4 v = *(const f32x4*)(ip + (size_t)(r0 + r) * C + c0 + 4 * cc);
        u16x4 w; w.x = f2bf(v.x); w.y = f2bf(v.y); w.z = f2bf(v.z); w.w = f2bf(v.w);
        *(u16x4*)(t + r * 68 + 4 * cc) = w;
    }
    __syncthreads();
#pragma unroll
    for (int j = 0; j < 4; ++j) {
        int id = tid + 256 * j;
        int c = id >> 4, rj = id & 15;
        u16x4 o;
        o.x = t[(4 * rj + 0) * 68 + c];
        o.y = t[(4 * rj + 1) * 68 + c];
        o.z = t[(4 * rj + 2) * 68 + c];
        o.w = t[(4 * rj + 3) * 68 + c];
        *(u16x4*)(op + (size_t)(c0 + c) * R + r0 + 4 * rj) = o;
    }
}

// ---------------- router: logits -> softmax -> top2 -> renormalized gates
__global__ __launch_bounds__(256)
void router_k(const float* __restrict__ x, const float* __restrict__ rw,
              int* __restrict__ counts, int* __restrict__ tE,
              int* __restrict__ tS, float* __restrict__ tG) {
    int wave = threadIdx.x >> 6, lane = threadIdx.x & 63;
    int t = blockIdx.x * 4 + wave;
    const float* xr = x + (size_t)t * DIM;
    float xv[16];
#pragma unroll
    for (int i = 0; i < 16; ++i) xv[i] = xr[lane + 64*i];
    float lg[NEXP];
#pragma unroll
    for (int e = 0; e < NEXP; ++e) {
        const float* wr_ = rw + e * DIM;
        float a = 0.f;
#pragma unroll
        for (int i = 0; i < 16; ++i) a += xv[i] * wr_[lane + 64*i];
        lg[e] = a;
    }
#pragma unroll
    for (int off = 32; off > 0; off >>= 1)
#pragma unroll
        for (int e = 0; e < NEXP; ++e) lg[e] += __shfl_xor(lg[e], off, 64);
    if (lane == 0) {
        float mx = lg[0];
        for (int e = 1; e < NEXP; ++e) mx = fmaxf(mx, lg[e]);
        float p[NEXP], s = 0.f;
        for (int e = 0; e < NEXP; ++e) { p[e] = expf(lg[e] - mx); s += p[e]; }
        float inv_s = 1.f / s;
        for (int e = 0; e < NEXP; ++e) p[e] *= inv_s;
        int i0 = 0;
        for (int e = 1; e < NEXP; ++e) if (p[e] > p[i0]) i0 = e;
        int i1 = (i0 == 0) ? 1 : 0;
        for (int e = 0; e < NEXP; ++e) if (e != i0 && p[e] > p[i1]) i1 = e;
        float v0 = p[i0], v1 = p[i1];
        float inv = 1.f / (v0 + v1 + 1e-9f);
        int s0 = atomicAdd(&counts[i0], 1);
        int s1 = atomicAdd(&counts[i1], 1);
        tE[2*t] = i0;  tE[2*t+1] = i1;
        tS[2*t] = s0;  tS[2*t+1] = s1;
        tG[2*t] = v0 * inv;  tG[2*t+1] = v1 * inv;
    }
}

// inline exclusive scan of 128-padded counts: returns base for expert e
__device__ __forceinline__ int pbase_of(const int* __restrict__ counts, int e) {
    int pb = 0;
#pragma unroll
    for (int i = 0; i < NEXP; ++i) {
        int pad = ((counts[i] + 127) >> 7) << 7;
        pb += (i < e) ? pad : 0;
    }
    return pb;
}

// ---------------- gather x rows (fp32) into packed bf16 rows per assignment
__global__ __launch_bounds__(256)
void gather_k(const float* __restrict__ x, const int* __restrict__ tE,
              const int* __restrict__ tS, const int* __restrict__ counts,
              u16* __restrict__ xg) {
    int a = blockIdx.x;              // 0..8191
    int t = a >> 1, k = a & 1;
    int e = tE[2*t + k];
    int row = pbase_of(counts, e) + tS[2*t + k];
    const f32x4* xr = (const f32x4*)(x + (size_t)t * DIM);
    u16x4* o = (u16x4*)(xg + (size_t)row * DIM);
    int i = threadIdx.x;             // 256 threads x 4 floats = 1024
    f32x4 v = xr[i];
    u16x4 r; r.x = f2bf(v.x); r.y = f2bf(v.y); r.z = f2bf(v.z); r.w = f2bf(v.w);
    o[i] = r;
}

// ---------------- grouped GEMM: C[row][col] = A[row][K_sub] * Bt[col][K_sub]  (per expert)
// m97 structure: 128x128 tile, BK=64, 4 waves, 4x4 of mfma_f32_16x16x32_bf16,
// global_load_lds width-16 staging, XOR-swizzled LDS (conflict-free, r3-verified).
// This round: strength-reduced addressing — staging pointers bumped +128B/iter,
// fragment ds_reads via 4 base pointers + compile-time immediate offsets
// (valid because (row&7)==(m16&7) is mi-invariant).
template<int K, int KSPLIT, bool GELU, typename OutT>
__global__ __launch_bounds__(256)
void gemm_bt(const u16* __restrict__ A, const u16* __restrict__ BtAll,
             OutT* __restrict__ C, const int* __restrict__ counts,
             int N, size_t cstride) {
    int e  = blockIdx.z / KSPLIT;
    int ks = blockIdx.z % KSPLIT;
    int cnt = counts[e];
    int mt = blockIdx.y;
    if (mt * 128 >= cnt) return;
    int row0 = pbase_of(counts, e) + mt * 128;
    const u16* Bt = BtAll + (size_t)e * N * K;
    OutT* Cp = C + (size_t)ks * cstride;
    int col0 = blockIdx.x * 128;
    const int kb0 = ks * (K / KSPLIT);
    constexpr int KITER = K / KSPLIT / 64;

    __shared__ __align__(16) u16 smem[128 * 128];   // As=[0,8K) Bs=[8K,16K); epilogue reuses 32 KB
    u16* As = smem;
    u16* Bs = smem + 128 * 64;

    int tid = threadIdx.x;
    int lane = tid & 63;
    int w = tid >> 6;
    int quad = lane >> 4, m16 = lane & 15;
    int wr = (w >> 1) * 64, wc = (w & 1) * 64;
    int rsub = lane >> 3;      // 0..7: row within an 8-row staging group
    int kch  = lane & 7;       // 16B chunk within row (LDS slot)
    int kchs = kch ^ rsub;     // swizzled GLOBAL chunk fetched into that slot

    // hoisted staging pointers (bumped +64 elem = 128 B per K-iter)
    const u16* ga[4];
    const u16* gb[4];
#pragma unroll
    for (int i = 0; i < 4; ++i) {
        int r = (w * 4 + i) * 8 + rsub;
        ga[i] = A  + (size_t)(row0 + r) * K + kb0 + kchs * 8;
        gb[i] = Bt + (size_t)(col0 + r) * K + kb0 + kchs * 8;
    }
    // hoisted fragment read bases; mi adds compile-time 1024-elem (2048 B) offsets
    int sw = m16 & 7;
    const u16* aP0 = As + (wr + m16) * 64 + ((quad       ^ sw) << 3);
    const u16* aP1 = As + (wr + m16) * 64 + (((4 + quad) ^ sw) << 3);
    const u16* bP0 = Bs + (wc + m16) * 64 + ((quad       ^ sw) << 3);
    const u16* bP1 = Bs + (wc + m16) * 64 + (((4 + quad) ^ sw) << 3);

    f32x4 acc[4][4] = {};

    for (int kit = 0; kit < KITER; ++kit) {
#pragma unroll
        for (int i = 0; i < 4; ++i) {
            int grp = w * 4 + i;
            __builtin_amdgcn_global_load_lds((gbl_uint*)ga[i], (lds_uint*)(As + grp * 512), 16, 0, 0);
            __builtin_amdgcn_global_load_lds((gbl_uint*)gb[i], (lds_uint*)(Bs + grp * 512), 16, 0, 0);
            ga[i] += 64; gb[i] += 64;
        }
        __syncthreads();
        {
            short8 af[4], bfr[4];
#pragma unroll
            for (int mi = 0; mi < 4; ++mi) af[mi]  = *(const short8*)(aP0 + mi * 1024);
#pragma unroll
            for (int ni = 0; ni < 4; ++ni) bfr[ni] = *(const short8*)(bP0 + ni * 1024);
#pragma unroll
            for (int mi = 0; mi < 4; ++mi)
#pragma unroll
                for (int ni = 0; ni < 4; ++ni)
                    acc[mi][ni] = __builtin_amdgcn_mfma_f32_16x16x32_bf16(af[mi], bfr[ni], acc[mi][ni], 0, 0, 0);
#pragma unroll
            for (int mi = 0; mi < 4; ++mi) af[mi]  = *(const short8*)(aP1 + mi * 1024);
#pragma unroll
            for (int ni = 0; ni < 4; ++ni) bfr[ni] = *(const short8*)(bP1 + ni * 1024);
#pragma unroll
            for (int mi = 0; mi < 4; ++mi)
#pragma unroll
                for (int ni = 0; ni < 4; ++ni)
                    acc[mi][ni] = __builtin_amdgcn_mfma_f32_16x16x32_bf16(af[mi], bfr[ni], acc[mi][ni], 0, 0, 0);
        }
        __syncthreads();
    }

    // epilogue: C/D layout col=lane&15, row=quad*4+reg
    if (GELU) {
        // stage bf16 tile in LDS (XOR-swizzled 16B chunks), then coalesced u16x8 stores
#pragma unroll
        for (int mi = 0; mi < 4; ++mi) {
#pragma unroll
            for (int r = 0; r < 4; ++r) {
                int row = wr + mi * 16 + quad * 4 + r;
#pragma unroll
                for (int ni = 0; ni < 4; ++ni) {
                    int col = wc + ni * 16 + m16;
                    int c16 = col >> 3, w8 = col & 7;
                    smem[row * 128 + (((c16 ^ (row & 15)) << 3) | w8)] = f2bf(gelu_f(acc[mi][ni][r]));
                }
            }
        }
        __syncthreads();
        int row_b = tid >> 4, c16_b = tid & 15;
        const u16* ls = smem + row_b * 128 + (((c16_b ^ (row_b & 15)) << 3));
        u16* gp = (u16*)Cp + (size_t)(row0 + row_b) * N + col0 + c16_b * 8;
#pragma unroll
        for (int j = 0; j < 8; ++j) {
            *(u16x8*)gp = *(const u16x8*)ls;
            ls += 16 * 128;
            gp += (size_t)16 * N;
        }
    } else {
        float* gp = (float*)Cp + (size_t)(row0 + wr + quad * 4) * N + col0 + wc + m16;
#pragma unroll
        for (int mi = 0; mi < 4; ++mi)
#pragma unroll
            for (int r = 0; r < 4; ++r) {
                float* rp = gp + (size_t)(mi * 16 + r) * N;
#pragma unroll
                for (int ni = 0; ni < 4; ++ni)
                    rp[ni * 16] = acc[mi][ni][r];
            }
    }
}

// ---------------- combine: out[t] = g0*(p0+p1)[row0(t)] + g1*(p0+p1)[row1(t)]
__global__ __launch_bounds__(256)
void combine_k(const float* __restrict__ p0, const float* __restrict__ p1,
               const int* __restrict__ tE, const int* __restrict__ tS,
               const float* __restrict__ tG, const int* __restrict__ counts,
               float* __restrict__ out) {
    int t = blockIdx.x;
    int e0 = tE[2*t], e1 = tE[2*t+1];
    int r0 = pbase_of(counts, e0) + tS[2*t];
    int r1 = pbase_of(counts, e1) + tS[2*t+1];
    float g0 = tG[2*t], g1 = tG[2*t+1];
    int i = threadIdx.x;
    f32x4 a0 = ((const f32x4*)(p0 + (size_t)r0 * DIM))[i];
    f32x4 b0 = ((const f32x4*)(p1 + (size_t)r0 * DIM))[i];
    f32x4 a1 = ((const f32x4*)(p0 + (size_t)r1 * DIM))[i];
    f32x4 b1 = ((const f32x4*)(p1 + (size_t)r1 * DIM))[i];
    f32x4* o = (f32x4*)(out + (size_t)t * DIM);
    o[i] = g0 * (a0 + b0) + g1 * (a1 + b1);
}

extern "C" void kernel_launch(void* const* d_in, const int* in_sizes, int n_in,
                              void* d_out, int out_size, void* d_ws, size_t ws_size,
                              hipStream_t stream) {
    const float* x  = (const float*)d_in[0];   // [4096,1024]
    const float* rw = (const float*)d_in[1];   // [8,1024]
    const float* w1 = (const float*)d_in[2];   // [8,1024,4096]
    const float* w2 = (const float*)d_in[3];   // [8,4096,1024]
    float* out = (float*)d_out;

    char* ws = (char*)d_ws;
    // layout (bytes):
    u16* w1t = (u16*)(ws + 0);                 // bf16 [E][H][D]   67,108,864
    u16* xg  = (u16*)(ws + 67108864ull);       // bf16 [9216][D]   18,874,368 -> 85,983,232
    u16* w2t = (u16*)(ws + 85983232ull);       // bf16 [E][D][H]   67,108,864 -> 153,092,096
    u16* hb  = (u16*)(ws + 153092096ull);      // bf16 [9216][H]   75,497,472 -> 228,589,568
    // fc2 split-K partials alias w1t+xg (dead after fc1): 2 x 37,748,736 = 75,497,472 <= 85,983,232
    float* p0 = (float*)(ws + 0);
    float* p1 = (float*)(ws + 37748736ull);
    int* ctrl   = (int*)(ws + 228589568ull);
    int* counts = ctrl;            // 8
    int* tE     = ctrl + 32;       // 8192
    int* tS     = ctrl + 32 + 8192;
    float* tG   = (float*)(ctrl + 32 + 16384);

    // fused transposes (+ counts zeroing, block 0)
    transpose_cast2<<<16384, 256, 0, stream>>>(w1, w1t, w2, w2t, counts);
    router_k<<<T_TOK / 4, 256, 0, stream>>>(x, rw, counts, tE, tS, tG);
    gather_k<<<T_TOK * 2, 256, 0, stream>>>(x, tE, tS, counts, xg);
    // fc1 + gelu: [rows x 1024] @ [1024 x 4096] -> hb (bf16)
    gemm_bt<DIM, 1, true, u16><<<dim3(HID / 128, 32, NEXP), 256, 0, stream>>>(
        xg, w1t, hb, counts, HID, 0);
    // fc2 split-K=2: [rows x 4096] @ [4096 x 1024] -> p0/p1 (f32)
    gemm_bt<HID, 2, false, float><<<dim3(DIM / 128, 32, NEXP * 2), 256, 0, stream>>>(
        hb, w2t, p0, counts, DIM, (size_t)MAXROWS * DIM);
    combine_k<<<T_TOK, 256, 0, stream>>>(p0, p1, tE, tS, tG, counts, out);
}